// Round 3
// baseline (248.014 us; speedup 1.0000x reference)
//
#include <hip/hip_runtime.h>
#include <hip/hip_bf16.h>

// NCC loss: five 9x9x9 box sums over (2,1,160,160,160) fp32, fully fused.
// Block owns 16x16 (h,w) tile, streams 20 outputs along D; D-window ring in
// registers (slot index compile-time via outer x unrolled-9 loop).
// Phase A: float4 halo staging (chunk-aligned OOB). Phase B: sliding-window
// row sums, 96 threads x 4 outputs. Phase C: 9-tap column sums, 1 out/thread.
// Double-buffered LDS -> 2 barriers/slice. launch_bounds(256,5): 5 blocks/CU.

#define NB   2
#define NDIM 160
#define TILE 16
#define RE   24                  // TILE + 8 halo
#define DCHUNK 20
#define NCH  (NDIM / DCHUNK)     // 8 chunks
#define PLANE (NDIM * NDIM)

__global__ __launch_bounds__(256, 5)
void ncc_main(const float* __restrict__ I, const float* __restrict__ J,
              double* __restrict__ out_acc) {
    const int t  = threadIdx.x;
    const int tx = t & 15;
    const int ty = t >> 4;
    const int w0 = blockIdx.x * TILE;
    const int h0 = blockIdx.y * TILE;
    const int b  = blockIdx.z / NCH;
    const int d0 = (blockIdx.z % NCH) * DCHUNK;

    const float* Ib = I + (size_t)b * NDIM * PLANE;
    const float* Jb = J + (size_t)b * NDIM * PLANE;

    // LDS, double-buffered. Row strides padded (7, 17) for bank spread.
    __shared__ float4 sI4[2][RE][7];       // halo, 6 chunks used + 1 pad
    __shared__ float4 sJ4[2][RE][7];
    __shared__ float4 rsv[2][RE][17];      // row sums {I, J, I2, J2}
    __shared__ float  rss[2][RE][17];      // row sums IJ
    __shared__ double wsum[4];

    // D-window ring in registers; slot j is always a compile-time constant.
    float ring[9][5];
#pragma unroll
    for (int k = 0; k < 9; ++k)
#pragma unroll
        for (int c = 0; c < 5; ++c) ring[k][c] = 0.0f;

    float acc[5] = {0.f, 0.f, 0.f, 0.f, 0.f};
    double csum = 0.0;
    int pb = 0;
    const float inv_win = 1.0f / 729.0f;

    // 36 steps: 28 real slices (dz = d0-4+step, clipped), 8 dummy.
    // Output d = d0 + step - 8 emitted for step in [8, 28).
    for (int o = 0; o < 4; ++o) {
#pragma unroll
        for (int j = 0; j < 9; ++j) {
            const int step = o * 9 + j;
            const int dz = d0 - 4 + step;
            float s[5] = {0.f, 0.f, 0.f, 0.f, 0.f};
            if (step < DCHUNK + 8 && dz >= 0 && dz < NDIM) {  // block-uniform
                const float* baseI = Ib + (size_t)dz * PLANE;
                const float* baseJ = Jb + (size_t)dz * PLANE;
                // ---- Phase A: stage 24x24 halo as aligned float4 chunks.
                // 288 items: field f, row r (24), chunk c (6).
                for (int e = t; e < 288; e += 256) {
                    int f   = e / 144;
                    int rem = e - f * 144;
                    int r   = rem / 6;
                    int c   = rem - r * 6;
                    int h = h0 - 4 + r;
                    int w = w0 - 4 + 4 * c;        // 16B aligned; chunk all-in/all-out
                    float4 v = make_float4(0.f, 0.f, 0.f, 0.f);
                    if ((unsigned)h < NDIM && (unsigned)w < NDIM) {
                        const float* src = (f ? baseJ : baseI) + h * NDIM + w;
                        v = *(const float4*)src;
                    }
                    if (f) sJ4[pb][r][c] = v; else sI4[pb][r][c] = v;
                }
                __syncthreads();
                // ---- Phase B: sliding 9-tap row sums along W.
                // 96 threads; thread = (row r, quad q) -> outputs 4q..4q+3.
                if (t < 96) {
                    int r = t >> 2, q = t & 3;
                    float4 i0 = sI4[pb][r][q], i1 = sI4[pb][r][q + 1], i2 = sI4[pb][r][q + 2];
                    float4 j0 = sJ4[pb][r][q], j1 = sJ4[pb][r][q + 1], j2 = sJ4[pb][r][q + 2];
                    float vi[12] = {i0.x,i0.y,i0.z,i0.w, i1.x,i1.y,i1.z,i1.w, i2.x,i2.y,i2.z,i2.w};
                    float vj[12] = {j0.x,j0.y,j0.z,j0.w, j1.x,j1.y,j1.z,j1.w, j2.x,j2.y,j2.z,j2.w};
                    int wo = q * 4;
                    float a0 = 0.f, a1 = 0.f, a2 = 0.f, a3 = 0.f, a4 = 0.f;
#pragma unroll
                    for (int k = 0; k < 9; ++k) {
                        a0 += vi[k]; a1 += vj[k];
                        a2 += vi[k] * vi[k]; a3 += vj[k] * vj[k]; a4 += vi[k] * vj[k];
                    }
                    rsv[pb][r][wo] = make_float4(a0, a1, a2, a3);
                    rss[pb][r][wo] = a4;
#pragma unroll
                    for (int m = 1; m < 4; ++m) {
                        float ai = vi[m + 8], si = vi[m - 1];
                        float aj = vj[m + 8], sj = vj[m - 1];
                        a0 += ai - si;
                        a1 += aj - sj;
                        a2 += ai * ai - si * si;
                        a3 += aj * aj - sj * sj;
                        a4 += ai * aj - si * sj;
                        rsv[pb][r][wo + m] = make_float4(a0, a1, a2, a3);
                        rss[pb][r][wo + m] = a4;
                    }
                }
                __syncthreads();
                // ---- Phase C: 9-tap column sums along H at (ty, tx).
                float s0 = 0.f, s1 = 0.f, s2 = 0.f, s3 = 0.f, s4 = 0.f;
#pragma unroll
                for (int k = 0; k < 9; ++k) {
                    float4 v = rsv[pb][ty + k][tx];
                    s0 += v.x; s1 += v.y; s2 += v.z; s3 += v.w;
                    s4 += rss[pb][ty + k][tx];
                }
                s[0] = s0; s[1] = s1; s[2] = s2; s[3] = s3; s[4] = s4;
                pb ^= 1;
            }
            // Slide the D-window (constant slot j -> registers).
#pragma unroll
            for (int c = 0; c < 5; ++c) {
                acc[c] += s[c] - ring[j][c];
                ring[j][c] = s[c];
            }
            if (step >= 8 && step < DCHUNK + 8) {
                float Is = acc[0], Js = acc[1];
                float I2 = acc[2], J2 = acc[3], IJ = acc[4];
                float cross = IJ - Is * Js * inv_win;
                float Ivar  = I2 - Is * Is * inv_win;
                float Jvar  = J2 - Js * Js * inv_win;
                float cc = cross * cross / (Ivar * Jvar + 1e-5f);
                csum += (double)cc;
            }
        }
    }

    // Block reduction: wave shuffle, then cross-wave via LDS.
#pragma unroll
    for (int off = 32; off > 0; off >>= 1)
        csum += __shfl_down(csum, off, 64);
    if ((t & 63) == 0) wsum[t >> 6] = csum;
    __syncthreads();
    if (t == 0) {
        double total = wsum[0] + wsum[1] + wsum[2] + wsum[3];
        atomicAdd(out_acc, total);
    }
}

__global__ void ncc_finalize(const double* __restrict__ acc,
                             float* __restrict__ out) {
    out[0] = (float)(-acc[0] / 8192000.0);
}

extern "C" void kernel_launch(void* const* d_in, const int* in_sizes, int n_in,
                              void* d_out, int out_size, void* d_ws, size_t ws_size,
                              hipStream_t stream) {
    const float* I = (const float*)d_in[0];   // y_true
    const float* J = (const float*)d_in[1];   // y_pred
    double* acc = (double*)d_ws;

    hipMemsetAsync(acc, 0, sizeof(double), stream);

    dim3 grid(NDIM / TILE, NDIM / TILE, NB * NCH);  // 10 x 10 x 16
    ncc_main<<<grid, 256, 0, stream>>>(I, J, acc);
    ncc_finalize<<<1, 1, 0, stream>>>(acc, (float*)d_out);
}